// Round 11
// baseline (1081.253 us; speedup 1.0000x reference)
//
#include <hip/hip_runtime.h>
#include <hip/hip_bf16.h>

typedef float f32x4 __attribute__((ext_vector_type(4)));
typedef short short8 __attribute__((ext_vector_type(8)));
typedef __bf16 bf16x8 __attribute__((ext_vector_type(8)));
typedef unsigned int u32x4 __attribute__((ext_vector_type(4)));

#define DI __device__ __forceinline__

constexpr int Bsz = 64;
constexpr int Fd  = 1024;
constexpr int Seq = 256;
constexpr int G4  = 4096;
constexpr int Mrows = Seq * Bsz;

DI float bf2f(unsigned short u) {
  union { unsigned int i; float f; } v; v.i = ((unsigned int)u) << 16; return v.f;
}
DI unsigned short f2bf(float f) {
  union { float ff; unsigned int i; } v; v.ff = f;
  unsigned int x = v.i;
  return (unsigned short)((x + 0x7fffu + ((x >> 16) & 1u)) >> 16);
}
DI float sigm(float x) { return 1.f / (1.f + __expf(-x)); }
DI float tanhfast(float x) {
  float e = __expf(-2.f * fabsf(x));
  float t = (1.f - e) / (1.f + e);
  return x < 0.f ? -t : t;
}
DI f32x4 mfma16(short8 a, short8 b, f32x4 c) {
  return __builtin_amdgcn_mfma_f32_16x16x32_bf16(
      __builtin_bit_cast(bf16x8, a), __builtin_bit_cast(bf16x8, b), c, 0, 0, 0);
}

// ---------- transpose x [B][F][S] f32 -> xs [S][B][F] bf16 ----------
__global__ void k_tx(const float* __restrict__ x, unsigned short* __restrict__ xs) {
  __shared__ float t[32][33];
  int b = blockIdx.z, f0 = blockIdx.y * 32, s0 = blockIdx.x * 32;
  int tx = threadIdx.x & 31, ty = threadIdx.x >> 5;
#pragma unroll
  for (int i = 0; i < 32; i += 8)
    t[ty + i][tx] = x[((size_t)b * Fd + f0 + ty + i) * Seq + s0 + tx];
  __syncthreads();
#pragma unroll
  for (int i = 0; i < 32; i += 8) {
    int s = s0 + ty + i, f = f0 + tx;
    xs[((size_t)s * Bsz + b) * Fd + f] = f2bf(t[tx][ty + i]);
  }
}

// ---------- transpose-convert [1024][4096] f32 -> [4096][1024] bf16 ----------
__global__ void k_tw(const float* __restrict__ in, unsigned short* __restrict__ out) {
  __shared__ float t[32][33];
  int n0 = blockIdx.x * 32, k0 = blockIdx.y * 32;
  int tx = threadIdx.x & 31, ty = threadIdx.x >> 5;
#pragma unroll
  for (int i = 0; i < 32; i += 8)
    t[ty + i][tx] = in[(size_t)(k0 + ty + i) * G4 + n0 + tx];
  __syncthreads();
#pragma unroll
  for (int i = 0; i < 32; i += 8)
    out[(size_t)(n0 + ty + i) * 1024 + k0 + tx] = f2bf(t[tx][ty + i]);
}

__global__ void k_zero(unsigned int* p, int n) {
  int i = blockIdx.x * 256 + threadIdx.x;
  if (i < n) p[i] = 0u;
}

// ---------- GEMM: C[16384][4096] bf16 = A[16384][1024] x Bt[4096][1024]^T ----------
__launch_bounds__(256, 2)
__global__ void k_gemm(const unsigned short* __restrict__ A,
                       const unsigned short* __restrict__ Bt,
                       unsigned short* __restrict__ C) {
  __shared__ unsigned short a_lds[128 * 64];
  __shared__ unsigned short b_lds[128 * 64];
  int bid = blockIdx.x;
  int tm = bid & 127, tn = bid >> 7;
  int tid = threadIdx.x, w = tid >> 6, l = tid & 63;
  int wm = w >> 1, wn = w & 1;
  f32x4 acc[4][4] = {};
  const unsigned short* Ab = A + (size_t)(tm * 128) * 1024;
  const unsigned short* Bb = Bt + (size_t)(tn * 128) * 1024;
  for (int kt = 0; kt < 16; ++kt) {
#pragma unroll
    for (int i = 0; i < 4; ++i) {
      int ci = tid + i * 256;
      int row = ci >> 3;
      int kB = (ci & 7) * 16;
      short8 va = *(const short8*)((const char*)(Ab + (size_t)row * 1024 + kt * 64) + kB);
      short8 vb = *(const short8*)((const char*)(Bb + (size_t)row * 1024 + kt * 64) + kB);
      int dst = row * 128 + (kB ^ ((row & 7) << 4));
      *(short8*)((char*)a_lds + dst) = va;
      *(short8*)((char*)b_lds + dst) = vb;
    }
    __syncthreads();
#pragma unroll
    for (int kb = 0; kb < 2; ++kb) {
      short8 af[4], bfv[4];
      int kByte = (kb * 32 + ((l >> 4) << 3)) * 2;
#pragma unroll
      for (int mi = 0; mi < 4; ++mi) {
        int row = wm * 64 + mi * 16 + (l & 15);
        af[mi] = *(const short8*)((const char*)a_lds + row * 128 + (kByte ^ ((row & 7) << 4)));
      }
#pragma unroll
      for (int ni = 0; ni < 4; ++ni) {
        int row = wn * 64 + ni * 16 + (l & 15);
        bfv[ni] = *(const short8*)((const char*)b_lds + row * 128 + (kByte ^ ((row & 7) << 4)));
      }
#pragma unroll
      for (int mi = 0; mi < 4; ++mi)
#pragma unroll
        for (int ni = 0; ni < 4; ++ni)
          acc[mi][ni] = mfma16(af[mi], bfv[ni], acc[mi][ni]);
    }
    __syncthreads();
  }
#pragma unroll
  for (int mi = 0; mi < 4; ++mi)
#pragma unroll
    for (int ni = 0; ni < 4; ++ni)
#pragma unroll
      for (int r = 0; r < 4; ++r) {
        int m = tm * 128 + wm * 64 + mi * 16 + ((l >> 4) << 2) + r;
        int n = tn * 128 + wn * 64 + ni * 16 + (l & 15);
        C[(size_t)m * G4 + n] = f2bf(acc[mi][ni][r]);
      }
}

// ---------- recurrence (r9 data path, TAG-FREE speculative protocol) ----------
// 256 blocks: rg = bid&3 (16 batch rows), jg = bid>>2 (16 hidden cols), 4 waves.
// Publish: self-validating dwords (low bf16 carries t&3 in 2 LSBs, high bf16
// carries 3-(t&3)) via sc0sc1, fire-and-forget. NO tag array, NO poll, NO
// drain. Consumers fetch h(t-1) SPECULATIVELY, verify embedded check bits,
// and re-fetch only stale 16B chunks (per-wave __any exit, s_sleep backoff).
// Safety: complementary encoding rejects 0xAA poison AND the launch-time
// zeroing of hbuf (cross-replay staleness); within a run the data dependency
// itself bounds skew to <=1 step (a block cannot publish h(t) before fully
// verifying h(t-1)), so mod-4 checks cannot alias. Liveness: the minimum-step
// blocks always have complete inputs, so the system always progresses.
__launch_bounds__(256, 1)
__global__ void k_rec(const unsigned short* __restrict__ xs,
                      const unsigned short* __restrict__ xWb,
                      const unsigned short* __restrict__ Ubt,
                      const float* __restrict__ bias,
                      unsigned int* __restrict__ hbuf,  // [2][64][512] dwords
                      float* __restrict__ out) {
  __shared__ unsigned short h_lds[16 * 1024];  // 32KB swizzled
  __shared__ float g_lds[16][68];              // padded
  __shared__ float obuf[256][17];
  int bid = blockIdx.x;
  int rg = bid & 3, jg = bid >> 2;
  int j0 = jg * 16;
  int tid = threadIdx.x, w = tid >> 6, l = tid & 63;

  int ncol = w * 1024 + j0 + (l & 15);
  const unsigned short* Urow = Ubt + (size_t)ncol * 1024;
  short8 ufr[32];
#pragma unroll
  for (int kb = 0; kb < 32; ++kb)
    ufr[kb] = *(const short8*)(Urow + kb * 32 + ((l >> 4) << 3));
  float bias_l = bias[ncol];

  int row2 = tid >> 4, jj = tid & 15;
  int pb = rg * 16 + row2, pj = j0 + jj;

  // fetch geometry: 8 x 16B per thread covers 16 rows x 512 dwords
  int fsrc[8], fdst[8];
#pragma unroll
  for (int i = 0; i < 8; ++i) {
    int ci = tid + i * 256;
    int row = ci >> 7;
    fsrc[i] = row * 512 + (ci & 127) * 4;
    fdst[i] = row * 2048 + (((ci & 127) * 16) ^ ((row & 7) << 4));
  }

  for (int t = 0; t < Seq; ++t) {
    // prefetch xW rows and x_t (cached)
    float xw[4];
#pragma unroll
    for (int r = 0; r < 4; ++r) {
      int m = rg * 16 + ((l >> 4) << 2) + r;
      xw[r] = bf2f(xWb[((size_t)t * 64 + m) * G4 + ncol]);
    }
    float xt = bf2f(xs[((size_t)t * 64 + pb) * Fd + pj]);

    f32x4 acc0 = {0.f, 0.f, 0.f, 0.f}, acc1 = {0.f, 0.f, 0.f, 0.f};
    f32x4 acc2 = {0.f, 0.f, 0.f, 0.f}, acc3 = {0.f, 0.f, 0.f, 0.f};
    if (t > 0) {
      // SPECULATIVE bulk fetch h(t-1): 32KB/block, 8 x dwordx4 per thread
      const unsigned int* hb_base = hbuf + (((t & 1) ^ 1) << 15) + (rg << 13);
      u32x4 cv[8];
#pragma unroll
      for (int i = 0; i < 8; ++i)
        asm volatile("global_load_dwordx4 %0, %1, off sc0 sc1"
                     : "=v"(cv[i]) : "v"(hb_base + fsrc[i]));
      asm volatile("s_waitcnt vmcnt(0)" ::: "memory");
      // verify check bits; granular re-fetch of stale 16B chunks only
      unsigned int tm1 = (unsigned int)(t - 1);
      unsigned int pat = (tm1 & 3u) | ((3u - (tm1 & 3u)) << 16);
      for (;;) {
        unsigned int badm = 0u;
#pragma unroll
        for (int i = 0; i < 8; ++i) {
          unsigned int bm = 0u;
#pragma unroll
          for (int q = 0; q < 4; ++q)
            bm |= (cv[i][q] & 0x00030003u) ^ pat;
          badm |= (bm ? 1u : 0u) << i;
        }
        if (!__any(badm != 0u)) break;
        __builtin_amdgcn_s_sleep(1);
#pragma unroll
        for (int i = 0; i < 8; ++i)
          if (badm & (1u << i))
            asm volatile("global_load_dwordx4 %0, %1, off sc0 sc1"
                         : "=v"(cv[i]) : "v"(hb_base + fsrc[i]));
        asm volatile("s_waitcnt vmcnt(0)" ::: "memory");
      }
      // stage to LDS (swizzled)
#pragma unroll
      for (int i = 0; i < 8; ++i)
        *(u32x4*)((char*)h_lds + fdst[i]) = cv[i];
      __syncthreads();
      // gates = h @ U : 32 MFMAs, 4 independent chains
      int arow = l & 15;
      const char* abase = (const char*)h_lds + arow * 2048;
      int sw = (arow & 7) << 4;
      int kres = (l >> 4) << 4;
#pragma unroll
      for (int kb = 0; kb < 32; kb += 4) {
        short8 a0 = *(const short8*)(abase + ((kb * 64 + kres) ^ sw));
        acc0 = mfma16(a0, ufr[kb], acc0);
        short8 a1 = *(const short8*)(abase + (((kb + 1) * 64 + kres) ^ sw));
        acc1 = mfma16(a1, ufr[kb + 1], acc1);
        short8 a2 = *(const short8*)(abase + (((kb + 2) * 64 + kres) ^ sw));
        acc2 = mfma16(a2, ufr[kb + 2], acc2);
        short8 a3 = *(const short8*)(abase + (((kb + 3) * 64 + kres) ^ sw));
        acc3 = mfma16(a3, ufr[kb + 3], acc3);
      }
    }
    // gates -> LDS (add xW + bias)
#pragma unroll
    for (int r = 0; r < 4; ++r)
      g_lds[((l >> 4) << 2) + r][w * 16 + (l & 15)] =
          acc0[r] + acc1[r] + acc2[r] + acc3[r] + xw[r] + bias_l;
    __syncthreads();
    // pointwise
    float iv = g_lds[row2][jj];
    float fv = g_lds[row2][16 + jj];
    float gv = g_lds[row2][32 + jj];
    float ov = g_lds[row2][48 + jj];
    float si = sigm(iv), sf = sigm(fv), tg = tanhfast(gv), so = sigm(ov);
    float cval = sf * xt + si * tg;
    float hval = so * tanhfast(cval);
    obuf[tid][t & 15] = hval;
    // publish self-validating h (fire-and-forget, no drain, no tag)
    {
      unsigned int chk = (jj & 1) ? (3u - ((unsigned int)t & 3u))
                                  : ((unsigned int)t & 3u);
      unsigned int hb = ((unsigned int)f2bf(hval) & 0xFFFCu) | chk;
      unsigned int ot = (unsigned int)__shfl_xor((int)hb, 1) & 0xFFFFu;
      if ((jj & 1) == 0) {
        unsigned int u = hb | (ot << 16);
        unsigned int* hp = hbuf + ((t & 1) << 15) + (pb << 9) + (pj >> 1);
        asm volatile("global_store_dword %0, %1, off sc0 sc1"
                     :: "v"(hp), "v"(u) : "memory");
      }
    }
    if (t == Seq - 1) {
      out[(size_t)16777216 + (size_t)pb * 1024 + pj] = hval;
      out[(size_t)16777216 + 65536 + (size_t)pb * 1024 + pj] = cval;
    }
    // protect h_lds reuse across iterations (all waves done with MFMA reads)
    __syncthreads();
    // off critical path: coalesced out flush every 16 steps
    if ((t & 15) == 15) {
      float* dst = out + ((size_t)pb * 1024 + pj) * Seq + (t - 15);
#pragma unroll
      for (int q = 0; q < 4; ++q) {
        f32x4 v = {obuf[tid][q * 4], obuf[tid][q * 4 + 1],
                   obuf[tid][q * 4 + 2], obuf[tid][q * 4 + 3]};
        *(f32x4*)(dst + q * 4) = v;
      }
    }
  }
}

extern "C" void kernel_launch(void* const* d_in, const int* in_sizes, int n_in,
                              void* d_out, int out_size, void* d_ws, size_t ws_size,
                              hipStream_t stream) {
  const float* x    = (const float*)d_in[0];
  const float* W    = (const float*)d_in[1];
  const float* U    = (const float*)d_in[2];
  const float* bias = (const float*)d_in[3];
  float* out = (float*)d_out;
  char* ws = (char*)d_ws;

  unsigned short* xs  = (unsigned short*)(ws);                       // 0..32MB
  unsigned short* Wbt = (unsigned short*)(ws + (size_t)33554432);    // 32..40MB
  unsigned short* Ubt = (unsigned short*)(ws + (size_t)41943040);    // 40..48MB
  unsigned short* xWb = (unsigned short*)(ws + (size_t)50331648);    // 48..176MB
  unsigned int* hbuf  = (unsigned int*)(ws + (size_t)184549376);     // 256KB

  k_tx<<<dim3(Seq / 32, Fd / 32, Bsz), 256, 0, stream>>>(x, xs);
  k_tw<<<dim3(G4 / 32, 1024 / 32), 256, 0, stream>>>(W, Wbt);
  k_tw<<<dim3(G4 / 32, 1024 / 32), 256, 0, stream>>>(U, Ubt);
  k_zero<<<256, 256, 0, stream>>>(hbuf, 65536);  // cross-replay invalidation
  k_gemm<<<dim3((Mrows / 128) * (G4 / 128)), 256, 0, stream>>>(xs, Wbt, xWb);
  k_rec<<<dim3(256), 256, 0, stream>>>(xs, xWb, Ubt, bias, hbuf, out);
}